// Round 5
// baseline (1517.173 us; speedup 1.0000x reference)
//
#include <hip/hip_runtime.h>

#define HH 64
#define WW 64
#define TT 100
#define CO 8
#define KS 6
#define LP 2
#define TS 16
#define HS 21          // TS + KS - 1
#define NS 441         // HS*HS halo sites
#define NG 5           // float4 per chunk = 20 timesteps
#define NCH 5          // chunks (5 x 20 t = 100)
#define NSLOT 2205     // NS * NG
#define NTHR 256

typedef float f32x4 __attribute__((ext_vector_type(4)));

__device__ __forceinline__ float stepu(float u, float s, float th, float wx) {
    // u = (u - s*th) + wx  -- exact reference association, no contraction
    return __fadd_rn(__fsub_rn(u, __fmul_rn(s, th)), wx);
}

#define FMA4(ACC, WD) \
    ACC.x = __fmaf_rn((WD), xv.x, ACC.x); \
    ACC.y = __fmaf_rn((WD), xv.y, ACC.y); \
    ACC.z = __fmaf_rn((WD), xv.z, ACC.z); \
    ACC.w = __fmaf_rn((WD), xv.w, ACC.w);

#define SCAN4(J) { \
    float u = ut[J], s = sprev[J]; unsigned m = 0u; \
    u = stepu(u, s, th, wx[J].x); s = (u > 0.f) ? 1.f : 0.f; m |= (u > 0.f) ? 1u : 0u; \
    u = stepu(u, s, th, wx[J].y); s = (u > 0.f) ? 1.f : 0.f; m |= (u > 0.f) ? 2u : 0u; \
    u = stepu(u, s, th, wx[J].z); s = (u > 0.f) ? 1.f : 0.f; m |= (u > 0.f) ? 4u : 0u; \
    u = stepu(u, s, th, wx[J].w); s = (u > 0.f) ? 1.f : 0.f; m |= (u > 0.f) ? 8u : 0u; \
    ut[J] = u; sprev[J] = s; cb[J] |= m << sh; }

__global__ __launch_bounds__(256, 2)
void sconv2d_spike_kernel(const float* __restrict__ x,
                          const float* __restrict__ wgt,
                          const float* __restrict__ thresh,
                          float* __restrict__ out)
{
    __shared__ float4   xs[NSLOT];              // 35.3 KB: one chunk [tg][site]
    __shared__ unsigned stg[NTHR * NCH * CO];   // 40 KB: [site][chunk][co] bits
    __shared__ float4   wds4[KS * KS][2];       // 1.2 KB: [tap][co-quartet]

    const int tid = threadIdx.x;
    for (int i = tid; i < KS * KS * CO; i += NTHR) {
        const int co  = i / (KS * KS);
        const int tap = i - co * (KS * KS);
        ((float*)wds4)[tap * 8 + co] = wgt[i];
    }
    const float th = thresh[0];

    // grid = 32 images x 16 tiles (4x4 of 16x16); 512 blocks = 2/CU exact
    const int blk = blockIdx.x;
    const int b   = blk >> 4;
    const int tb  = blk & 15;
    const int h0  = (tb >> 2) << 4;
    const int w0  = (tb & 3) << 4;
    const int r   = tid >> 4;
    const int c   = tid & 15;

    const float* xb = x + (size_t)b * (HH * WW * TT);

    float ut[CO], sprev[CO];
#pragma unroll
    for (int j = 0; j < CO; ++j) { ut[j] = 0.f; sprev[j] = 0.f; }

    const int rbase = r * HS + c;

#pragma unroll 1
    for (int g = 0; g < NCH; ++g) {
        const int t0 = g * 20;

        // ---- stage chunk [t0, t0+20) into xs[tg*NS + site]; zero-pad halo ----
#pragma unroll
        for (int k = 0; k < 9; ++k) {
            const int i = tid + (k << 8);
            if (i < NSLOT) {
                const int site = i / NG;
                const int tg   = i - site * NG;
                const int hr   = site / HS;
                const int hc   = site - hr * HS;
                const int hh   = h0 - LP + hr;
                const int ww   = w0 - LP + hc;
                float4 v = make_float4(0.f, 0.f, 0.f, 0.f);
                if ((unsigned)hh < (unsigned)HH && (unsigned)ww < (unsigned)WW)
                    v = *(const float4*)(xb + (hh * WW + ww) * TT + t0 + tg * 4);
                xs[tg * NS + site] = v;
            }
        }
        __syncthreads();

        // ---- compute: conv (kh-major, kw-inner FMA chain, bit-exact) + scan ----
        unsigned cb[CO];
#pragma unroll
        for (int j = 0; j < CO; ++j) cb[j] = 0u;

#pragma unroll 1                 // rolled tg: body ~5 KB, I$-resident
        for (int tgl = 0; tgl < NG; ++tgl) {
            const float4* xrow = xs + tgl * NS + rbase;
            float4 wx[CO];
#pragma unroll
            for (int j = 0; j < CO; ++j) wx[j] = make_float4(0.f, 0.f, 0.f, 0.f);
#pragma unroll
            for (int kh = 0; kh < KS; ++kh) {
#pragma unroll
                for (int kw = 0; kw < KS; ++kw) {
                    const float4 xv = xrow[kh * HS + kw];
                    const float4 wa = wds4[kh * KS + kw][0];   // couts 0..3
                    const float4 wb = wds4[kh * KS + kw][1];   // couts 4..7
                    FMA4(wx[0], wa.x); FMA4(wx[1], wa.y);
                    FMA4(wx[2], wa.z); FMA4(wx[3], wa.w);
                    FMA4(wx[4], wb.x); FMA4(wx[5], wb.y);
                    FMA4(wx[6], wb.z); FMA4(wx[7], wb.w);
                }
            }
            const int sh = tgl * 4;
            SCAN4(0); SCAN4(1); SCAN4(2); SCAN4(3);
            SCAN4(4); SCAN4(5); SCAN4(6); SCAN4(7);
        }

        // chunk bits straight to LDS (no per-thread bw[] registers)
#pragma unroll
        for (int j = 0; j < CO; ++j)
            stg[(tid * NCH + g) * CO + j] = cb[j];
        __syncthreads();   // xs consumed before next stage overwrites it
    }

    // ---- flush: bit expansion, contiguous nontemporal float4 stores ----
    float* outb = out + (size_t)b * (CO * HH * WW * TT);
#pragma unroll 1
    for (int k = 0; k < 200; ++k) {
        const int idx = tid + (k << 8);       // 0..51199
        const int co  = idx / 6400;
        const int rem = idx - co * 6400;
        const int u   = rem / 25;             // site 0..255 (== computing tid)
        const int q   = rem - u * 25;
        const int tt  = q * 4;                // 0..96
        const int g   = q / NG;               // chunk (tt/20)
        const int sh  = tt - g * 20;          // bit offset, <= 16
        const unsigned bs = stg[(u * NCH + g) * CO + co] >> sh;
        f32x4 v;
        v.x = (float)( bs        & 1u);
        v.y = (float)((bs >> 1)  & 1u);
        v.z = (float)((bs >> 2)  & 1u);
        v.w = (float)((bs >> 3)  & 1u);
        f32x4* dst = (f32x4*)(outb + (((size_t)co * HH + (h0 + (u >> 4))) * WW
                                      + (w0 + (u & 15))) * TT + tt);
        __builtin_nontemporal_store(v, dst);
    }
}

extern "C" void kernel_launch(void* const* d_in, const int* in_sizes, int n_in,
                              void* d_out, int out_size, void* d_ws, size_t ws_size,
                              hipStream_t stream) {
    const float* x      = (const float*)d_in[0];
    const float* wgt    = (const float*)d_in[1];
    const float* thresh = (const float*)d_in[2];
    float* out = (float*)d_out;
    (void)d_ws; (void)ws_size;

    sconv2d_spike_kernel<<<dim3(32 * 16), dim3(NTHR), 0, stream>>>(x, wgt, thresh, out);
}